// Round 14
// baseline (459.526 us; speedup 1.0000x reference)
//
#include <hip/hip_runtime.h>
#include <hip/hip_fp16.h>

// Graph-attention sequential sweep as dataflow over the dependency DAG.
// Node i depends only on rows g[j] for j in neighbors[i], j<i, k<deg[i].
//
// R14 = R11 (verified 189us attn / 368.5us total: f16-only pool, decoupled
// scalar/row chains, inline f32 out writes) + ONE change: 2048 blocks
// (8 blocks/CU, 32 waves/CU) via __launch_bounds__(256,8).
//  Rationale: R12 (nt stores) and R13 (f32 stream removed) both left FETCH
//  pinned at ~424MB -> the capacity/eviction theory is DEAD. FETCH is
//  structural per-XCD L2 miss traffic of a random 1KB gather over a 102MB
//  pool (8x4MB private L2s can't hold it); misses are served by the
//  memory-side Infinity Cache. The only prior occupancy test on this
//  structure (R6) was confounded with precomp fusion. Clean retest:
//  if the gather is latency/parallelism-limited at ~2.8-3.1 TB/s, doubling
//  co-resident waves should cut attn time substantially.
//
// Lessons: R4 consecutive ids on distinct waves; R5 no global atomic
// counter; R7 f16 gather mirror; R8/R12 nt hints useless; R10 scalar ej
// chain decoupled; R11 center row from feats16; R13 separate expand pass
// is net-negative (inline f32 write is cheaper).
//
// Deadlock-freedom: all 8192 waves co-resident (8 blocks/CU x 256 CU,
// LDS=0, VGPR<=64 required, kernel measures 44). Induction per sweep:
// smallest id with unpublished SCALAR has all scalar deps (<id) published
// -> progress; smallest id with unset ROW flag has all row deps (<id) set
// -> progress.
//
// Coherence (NO buffer_inv / NO buffer_wbl2):
//  - ej_new: scalar payload+flag word (bits==0 => not ready; +0.0 nudged to
//    denormal), relaxed agent atomic store/load, no ordering needed.
//  - out16 rows: write-through to LLC (sc0 sc1); row_flag set only after
//    s_waitcnt(0) drains the row; consumers read rows with NORMAL cached
//    loads, first touch only after row_flag seen -> no stale copies.

constexpr int NN   = 50000;
constexpr int D    = 512;
constexpr int K    = 32;
constexpr int D4   = D / 4;   // 128 float4 per f32 row
constexpr int DU16 = D / 2;   // 256 u32 per f16 row (512 halves)

typedef float        v4f __attribute__((ext_vector_type(4)));
typedef unsigned int v4u __attribute__((ext_vector_type(4)));

__device__ __forceinline__ void store_u4_llc(unsigned int* p, v4u v) {
    asm volatile("global_store_dwordx4 %0, %1, off sc0 sc1"
                 :: "v"(p), "v"(v) : "memory");
}
__device__ __forceinline__ void store_f4_llc(float* p, float4 v) {
    v4f vv; vv.x = v.x; vv.y = v.y; vv.z = v.z; vv.w = v.w;
    asm volatile("global_store_dwordx4 %0, %1, off sc0 sc1"
                 :: "v"(p), "v"(vv) : "memory");
}
__device__ __forceinline__ unsigned int packh2(float a, float b) {
    __half2 h = __floats2half2_rn(a, b);
    return *reinterpret_cast<unsigned int*>(&h);
}
__device__ __forceinline__ float2 unpackh2(unsigned int u) {
    __half2 h = *reinterpret_cast<__half2*>(&u);
    return __half22float2(h);
}

__global__ __launch_bounds__(256) void precomp_kernel(
    const float* __restrict__ feats,
    const float* __restrict__ wq_w, const float* __restrict__ wq_b,
    const float* __restrict__ wk_w, const float* __restrict__ wk_b,
    float* __restrict__ ei, float* __restrict__ ej_orig,
    unsigned int* __restrict__ feats16)   // may be null (f32 fallback path)
{
    int gw   = (int)((blockIdx.x * blockDim.x + threadIdx.x) >> 6); // global wave id
    int lane = threadIdx.x & 63;
    if (gw >= NN) return;
    const float4* row = (const float4*)feats + (size_t)gw * D4;
    const float4* q4  = (const float4*)wq_w;
    const float4* k4  = (const float4*)wk_w;
    // lane owns elements [8*lane .. 8*lane+7]
    float4 v0 = row[2 * lane], v1 = row[2 * lane + 1];
    float4 q0 = q4[2 * lane],  q1 = q4[2 * lane + 1];
    float4 k0 = k4[2 * lane],  k1 = k4[2 * lane + 1];
    float dq = v0.x*q0.x + v0.y*q0.y + v0.z*q0.z + v0.w*q0.w
             + v1.x*q1.x + v1.y*q1.y + v1.z*q1.z + v1.w*q1.w;
    float dk = v0.x*k0.x + v0.y*k0.y + v0.z*k0.z + v0.w*k0.w
             + v1.x*k1.x + v1.y*k1.y + v1.z*k1.z + v1.w*k1.w;
#pragma unroll
    for (int off = 32; off > 0; off >>= 1) {
        dq += __shfl_down(dq, off, 64);
        dk += __shfl_down(dk, off, 64);
    }
    if (feats16) {
        v4u p;
        p.x = packh2(v0.x, v0.y); p.y = packh2(v0.z, v0.w);
        p.z = packh2(v1.x, v1.y); p.w = packh2(v1.z, v1.w);
        *(v4u*)(feats16 + (size_t)gw * DU16 + 4 * lane) = p;  // plain store;
        // visible to the attn kernel via stream-order kernel boundary.
    }
    if (lane == 0) {
        ei[gw]      = dq + wq_b[0];
        ej_orig[gw] = dk + wk_b[0];
    }
}

// ---------------- fp16-gather dataflow kernel (primary path) ----------------
__global__ __launch_bounds__(256, 8) void attn_dataflow_h16(
    const int* __restrict__ neighbors, const int* __restrict__ deg,
    const float* __restrict__ ei_arr, const float* __restrict__ ej_orig,
    const float* __restrict__ wk_b,
    const unsigned int* __restrict__ feats16, unsigned int* __restrict__ out16,
    int* ej_new, int* row_flag, float* out)
{
    const int lane   = threadIdx.x & 63;
    const int gwave  = (int)((blockIdx.x * blockDim.x + threadIdx.x) >> 6);
    const int nwaves = (int)((gridDim.x * blockDim.x) >> 6);
    const float   wkb = wk_b[0];

    for (int id = gwave; id < NN; id += nwaves) {
        const int d = deg[id];
        int nbr = 0;
        if (lane < K) nbr = neighbors[(size_t)id * K + lane];
        const bool valid = lane < d;                 // d <= 32
        const bool isdep = valid && (nbr < id);

        // center row from the f16 mirror (16B/lane; no f32 feats stream here)
        const v4u cp = *(const v4u*)(feats16 + (size_t)id * DU16 + 4 * lane);
        float2 cf0 = unpackh2(cp.x), cf1 = unpackh2(cp.y);
        float2 cf2 = unpackh2(cp.z), cf3 = unpackh2(cp.w);
        const float4 c0 = {cf0.x, cf0.y, cf1.x, cf1.y};
        const float4 c1 = {cf2.x, cf2.y, cf3.x, cf3.y};
        const float eii  = ei_arr[id];
        const float ejoc = ej_orig[id];   // own w_k(feats[id]) — exact

        float ejraw = 0.f, eij = -3.0e38f;
        if (valid && !isdep) { ejraw = ej_orig[nbr]; eij = eii * ejraw; }

        // ---------------- phase A: scalar chain ----------------
        unsigned long long wait = __ballot(isdep);
        while (wait) {
            int pv = 0;
            const bool w = (wait >> lane) & 1ULL;
            if (w) pv = __hip_atomic_load(&ej_new[nbr], __ATOMIC_RELAXED,
                                          __HIP_MEMORY_SCOPE_AGENT);
            unsigned long long ready = __ballot(w && pv != 0);
            if (w && pv != 0) { ejraw = __int_as_float(pv); eij = eii * ejraw; }
            wait &= ~ready;
            if (wait && !ready) __builtin_amdgcn_s_sleep(1);
        }
        // exact 2-pass softmax scalars (all eij known; invalid = -3e38)
        float m = eij;
#pragma unroll
        for (int off = 32; off > 0; off >>= 1)
            m = fmaxf(m, __shfl_xor(m, off, 64));
        const float wt = valid ? __expf(eij - m) : 0.f;
        float s = wt, se = wt * ejraw;
#pragma unroll
        for (int off = 32; off > 0; off >>= 1) {
            s  += __shfl_xor(s,  off, 64);
            se += __shfl_xor(se, off, 64);
        }
        const float inv_s = (s > 0.f) ? (1.0f / s) : 0.f;

        // publish ej_new NOW — scalar-only payload, no drain needed
        {
            const float ejn = ejoc + ((s > 0.f) ? (se * inv_s - wkb) : 0.f);
            int bits = __float_as_int(ejn);
            if (bits == 0) bits = 1;   // avoid the not-ready sentinel
            if (lane == 0)
                __hip_atomic_store(&ej_new[id], bits,
                                   __ATOMIC_RELAXED, __HIP_MEMORY_SCOPE_AGENT);
        }

        // ---------------- phase B: row chain ----------------
        float4 acc0 = {0.f, 0.f, 0.f, 0.f};
        float4 acc1 = {0.f, 0.f, 0.f, 0.f};
        unsigned long long pend  = __ballot(valid && !isdep);
        unsigned long long wait2 = __ballot(isdep);

        while (pend | wait2) {
            if (!pend) {
                int rv = 0;
                const bool w = (wait2 >> lane) & 1ULL;
                if (w) rv = __hip_atomic_load(&row_flag[nbr], __ATOMIC_RELAXED,
                                              __HIP_MEMORY_SCOPE_AGENT);
                unsigned long long ready = __ballot(w && rv != 0);
                if (!ready) { __builtin_amdgcn_s_sleep(1); continue; }
                pend = ready;
                wait2 &= ~ready;
            }
            // take up to 8 ready neighbors; static indexing, duplicates
            // clamp to the last valid slot and get weight 0.
            int js_[8]; float ww[8]; int klast = 0;
#pragma unroll
            for (int t = 0; t < 8; ++t) {
                const bool has = (pend != 0);            // wave-uniform
                int k = has ? ((int)__ffsll(pend) - 1) : klast;
                if (has) pend &= pend - 1;
                klast = k;
                float w8 = __shfl(wt, k, 64);
                ww[t]  = has ? w8 : 0.f;
                js_[t] = __shfl(nbr, k, 64);
            }
            v4u pv8[8];
#pragma unroll
            for (int t = 0; t < 8; ++t) {
                const unsigned int* sp = ((js_[t] < id) ? out16 : feats16)
                                         + (size_t)js_[t] * DU16 + 4 * lane;
                pv8[t] = *(const v4u*)sp;
            }
#pragma unroll
            for (int t = 0; t < 8; ++t) {
                const float a = ww[t];
                float2 f0 = unpackh2(pv8[t].x), f1 = unpackh2(pv8[t].y);
                float2 f2 = unpackh2(pv8[t].z), f3 = unpackh2(pv8[t].w);
                acc0.x += a * f0.x; acc0.y += a * f0.y;
                acc0.z += a * f1.x; acc0.w += a * f1.y;
                acc1.x += a * f2.x; acc1.y += a * f2.y;
                acc1.z += a * f3.x; acc1.w += a * f3.y;
            }
        }

        float4 g0 = {c0.x + acc0.x * inv_s, c0.y + acc0.y * inv_s,
                     c0.z + acc0.z * inv_s, c0.w + acc0.w * inv_s};
        float4 g1 = {c1.x + acc1.x * inv_s, c1.y + acc1.y * inv_s,
                     c1.z + acc1.z * inv_s, c1.w + acc1.w * inv_s};

        // f16 mirror row: the gather payload, write-through + flag-ordered
        v4u pg;
        pg.x = packh2(g0.x, g0.y); pg.y = packh2(g0.z, g0.w);
        pg.z = packh2(g1.x, g1.y); pg.w = packh2(g1.z, g1.w);
        store_u4_llc(out16 + (size_t)id * DU16 + 4 * lane, pg);

        // order the out16 payload (at LLC) before the row flag
        __builtin_amdgcn_s_waitcnt(0);
        if (lane == 0)
            __hip_atomic_store(&row_flag[id], 1,
                               __ATOMIC_RELAXED, __HIP_MEMORY_SCOPE_AGENT);

        // f32 result row: no device consumer -> plain cached stores, off-chain
        float4* orow4 = (float4*)out + (size_t)id * D4;
        orow4[2 * lane]     = g0;
        orow4[2 * lane + 1] = g1;
    }
}

// ---------------- f32 fallback (verbatim R5 kernel, 260us verified) ---------
__global__ __launch_bounds__(256, 4) void attn_dataflow_f32(
    const float* __restrict__ feats,
    const int* __restrict__ neighbors, const int* __restrict__ deg,
    const float* __restrict__ ei_arr, const float* __restrict__ ej_orig,
    const float* __restrict__ wk_w, const float* __restrict__ wk_b,
    int* ej_new, float* out)
{
    const int lane   = threadIdx.x & 63;
    const int gwave  = (int)((blockIdx.x * blockDim.x + threadIdx.x) >> 6);
    const int nwaves = (int)((gridDim.x * blockDim.x) >> 6);
    const float4* f4  = (const float4*)feats;
    const float4* o4r = (const float4*)out;
    const float4* wk4 = (const float4*)wk_w;
    const float   wkb = wk_b[0];

    for (int id = gwave; id < NN; id += nwaves) {
        const int d = deg[id];
        int nbr = 0;
        if (lane < K) nbr = neighbors[(size_t)id * K + lane];
        const bool valid = lane < d;
        const bool isdep = valid && (nbr < id);

        const float4 c0 = f4[(size_t)id * D4 + lane];
        const float4 c1 = f4[(size_t)id * D4 + lane + 64];
        const float eii = ei_arr[id];

        float eij = 0.f;
        if (valid && !isdep) eij = eii * ej_orig[nbr];

        float4 acc0 = {0.f, 0.f, 0.f, 0.f};
        float4 acc1 = {0.f, 0.f, 0.f, 0.f};
        float m = -3.0e38f, s = 0.f;

        unsigned long long pend = __ballot(valid && !isdep);
        unsigned long long wait = __ballot(isdep);

        while (pend | wait) {
            if (!pend) {
                int pv = 0;
                const bool w = (wait >> lane) & 1ULL;
                if (w) pv = __hip_atomic_load(&ej_new[nbr], __ATOMIC_RELAXED,
                                              __HIP_MEMORY_SCOPE_AGENT);
                unsigned long long ready = __ballot(w && pv != 0);
                if (!ready) { __builtin_amdgcn_s_sleep(1); continue; }
                if (w && pv != 0) eij = eii * __int_as_float(pv);
                pend = ready;
                wait &= ~ready;
            }
            int cnt = 0;
            int   js[4]; float ee[4];
#pragma unroll
            for (int t = 0; t < 4; ++t) {
                if (pend) {
                    int k = (int)__ffsll(pend) - 1;
                    pend &= pend - 1;
                    ee[cnt] = __shfl(eij, k, 64);
                    js[cnt] = __shfl(nbr, k, 64);
                    ++cnt;
                }
            }
            float4 v0[4], v1[4];
#pragma unroll
            for (int t = 0; t < 4; ++t) {
                if (t < cnt) {
                    const float4* sp = (js[t] < id) ? (o4r + (size_t)js[t] * D4)
                                                    : (f4  + (size_t)js[t] * D4);
                    v0[t] = sp[lane];
                    v1[t] = sp[lane + 64];
                }
            }
            float mb = m;
#pragma unroll
            for (int t = 0; t < 4; ++t) if (t < cnt) mb = fmaxf(mb, ee[t]);
            if (mb > m) {
                const float r = __expf(m - mb);
                acc0.x *= r; acc0.y *= r; acc0.z *= r; acc0.w *= r;
                acc1.x *= r; acc1.y *= r; acc1.z *= r; acc1.w *= r;
                s *= r; m = mb;
            }
#pragma unroll
            for (int t = 0; t < 4; ++t) {
                if (t < cnt) {
                    const float wt = __expf(ee[t] - m);
                    s += wt;
                    acc0.x += wt * v0[t].x; acc0.y += wt * v0[t].y;
                    acc0.z += wt * v0[t].z; acc0.w += wt * v0[t].w;
                    acc1.x += wt * v1[t].x; acc1.y += wt * v1[t].y;
                    acc1.z += wt * v1[t].z; acc1.w += wt * v1[t].w;
                }
            }
        }

        const float inv_s = (s > 0.f) ? (1.0f / s) : 0.f;
        float4 g0 = {c0.x + acc0.x * inv_s, c0.y + acc0.y * inv_s,
                     c0.z + acc0.z * inv_s, c0.w + acc0.w * inv_s};
        float4 g1 = {c1.x + acc1.x * inv_s, c1.y + acc1.y * inv_s,
                     c1.z + acc1.z * inv_s, c1.w + acc1.w * inv_s};
        float* orow = out + (size_t)id * D;
        store_f4_llc(orow + 4 * lane,        g0);
        store_f4_llc(orow + 4 * (lane + 64), g1);

        float4 w0 = wk4[lane], w1 = wk4[lane + 64];
        float pd = g0.x * w0.x + g0.y * w0.y + g0.z * w0.z + g0.w * w0.w
                 + g1.x * w1.x + g1.y * w1.y + g1.z * w1.z + g1.w * w1.w;
#pragma unroll
        for (int off = 32; off > 0; off >>= 1)
            pd += __shfl_xor(pd, off, 64);

        int bits = __float_as_int(pd + wkb);
        if (bits == 0) bits = 1;

        __builtin_amdgcn_s_waitcnt(0);
        if (lane == 0)
            __hip_atomic_store(&ej_new[id], bits,
                               __ATOMIC_RELAXED, __HIP_MEMORY_SCOPE_AGENT);
    }
}

extern "C" void kernel_launch(void* const* d_in, const int* in_sizes, int n_in,
                              void* d_out, int out_size, void* d_ws, size_t ws_size,
                              hipStream_t stream)
{
    const float* feats     = (const float*)d_in[0];
    const float* wq_w      = (const float*)d_in[1];
    const float* wq_b      = (const float*)d_in[2];
    const float* wk_w      = (const float*)d_in[3];
    const float* wk_b      = (const float*)d_in[4];
    const int*   neighbors = (const int*)d_in[5];
    const int*   deg       = (const int*)d_in[6];
    float*       out       = (float*)d_out;

    // ws: [ej_new: NN i][pad 64][row_flag: NN i][pad 64][ei: NN f][ej_orig: NN f]
    //     | align1024 | [feats16: NN*1KB][out16: NN*1KB]  (if ws_size allows)
    char*  ws       = (char*)d_ws;
    int*   ej_new   = (int*)ws;
    int*   row_flag = ej_new + NN + 64;
    float* ei       = (float*)(row_flag + NN + 64);
    float* ej_orig  = ei + NN;
    size_t scal_end = (size_t)((char*)(ej_orig + NN) - ws);
    size_t f16_off  = (scal_end + 1023) & ~(size_t)1023;
    size_t f16_need = 2ull * NN * DU16 * sizeof(unsigned int);  // 102.4 MB
    const bool use16 = (ws_size >= f16_off + f16_need);
    unsigned int* feats16 = (unsigned int*)(ws + f16_off);
    unsigned int* out16   = feats16 + (size_t)NN * DU16;

    // zero ej_new + pad + row_flag
    (void)hipMemsetAsync(d_ws, 0, (size_t)(2 * NN + 128) * sizeof(int), stream);

    dim3 pb(256), pg((NN + 3) / 4);
    precomp_kernel<<<pg, pb, 0, stream>>>(feats, wq_w, wq_b, wk_w, wk_b,
                                          ei, ej_orig, use16 ? feats16 : nullptr);

    if (use16) {
        // R14: 2048 blocks = 8192 waves co-resident (8 blocks/CU, VGPR 44 <= 64)
        attn_dataflow_h16<<<dim3(2048), dim3(256), 0, stream>>>(
            neighbors, deg, ei, ej_orig, wk_b,
            feats16, out16, ej_new, row_flag, out);
    } else {
        attn_dataflow_f32<<<dim3(1024), dim3(256), 0, stream>>>(
            feats, neighbors, deg, ei, ej_orig, wk_w, wk_b, ej_new, out);
    }
}

// Round 15
// 367.153 us; speedup vs baseline: 1.2516x; 1.2516x over previous
//
#include <hip/hip_runtime.h>
#include <hip/hip_fp16.h>

// Graph-attention sequential sweep as dataflow over the dependency DAG.
// Node i depends only on rows g[j] for j in neighbors[i], j<i, k<deg[i].
//
// R15 = R11 (verified best: 189us attn / 368.5us total; f16-only pool,
// decoupled scalar/row chains, inline f32 out, 1024 blocks) + two cuts:
//  (1) ws memset folded into precomp (tid<NN zeroes ej_new/row_flag) —
//      one fewer dispatch in the critical stream.
//  (2) software-pipelined per-id FRONT in attn: next id's deg/neighbors/
//      center-row/ei/ej_orig loads issued right after the scalar publish,
//      overlapping phase B. Kills the ~2000cy serial preamble chain per
//      iteration (~12 iters/wave).
//
// Dead levers (measured): occupancy >16 waves/CU (R6/R14: +traffic,
// +time); nt hints (R8/R12: memory-side LLC allocates everything);
// LLC-capacity theory (R12/R13: FETCH pinned ~425MB = structural L2-miss
// of random 1KB gather over 102MB pool); separate expand pass (R13:
// net-negative); atomic counter (R5: -60%); GRAB-batching (R4: 10x worse).
//
// Deadlock-freedom: all 4096 waves co-resident (4 blocks/CU x 256 CU,
// LDS=0, VGPR<=128 via __launch_bounds__(256,4)). Induction per sweep:
// smallest id with unpublished SCALAR has all scalar deps (<id) published
// -> progress; smallest id with unset ROW flag has all row deps (<id) set
// -> progress.
//
// Coherence (NO buffer_inv / NO buffer_wbl2):
//  - ej_new: scalar payload+flag word (bits==0 => not ready; +0.0 nudged
//    to denormal), relaxed agent atomic store/load, no ordering needed.
//  - out16 rows: write-through to LLC (sc0 sc1); row_flag set only after
//    s_waitcnt(0) drains the row; consumers read rows with NORMAL cached
//    loads, first touch only after row_flag seen -> no stale copies.

constexpr int NN   = 50000;
constexpr int D    = 512;
constexpr int K    = 32;
constexpr int D4   = D / 4;   // 128 float4 per f32 row
constexpr int DU16 = D / 2;   // 256 u32 per f16 row (512 halves)

typedef float        v4f __attribute__((ext_vector_type(4)));
typedef unsigned int v4u __attribute__((ext_vector_type(4)));

__device__ __forceinline__ void store_u4_llc(unsigned int* p, v4u v) {
    asm volatile("global_store_dwordx4 %0, %1, off sc0 sc1"
                 :: "v"(p), "v"(v) : "memory");
}
__device__ __forceinline__ void store_f4_llc(float* p, float4 v) {
    v4f vv; vv.x = v.x; vv.y = v.y; vv.z = v.z; vv.w = v.w;
    asm volatile("global_store_dwordx4 %0, %1, off sc0 sc1"
                 :: "v"(p), "v"(vv) : "memory");
}
__device__ __forceinline__ unsigned int packh2(float a, float b) {
    __half2 h = __floats2half2_rn(a, b);
    return *reinterpret_cast<unsigned int*>(&h);
}
__device__ __forceinline__ float2 unpackh2(unsigned int u) {
    __half2 h = *reinterpret_cast<__half2*>(&u);
    return __half22float2(h);
}

__global__ __launch_bounds__(256) void precomp_kernel(
    const float* __restrict__ feats,
    const float* __restrict__ wq_w, const float* __restrict__ wq_b,
    const float* __restrict__ wk_w, const float* __restrict__ wk_b,
    float* __restrict__ ei, float* __restrict__ ej_orig,
    unsigned int* __restrict__ feats16,   // may be null (f32 fallback path)
    int* __restrict__ ej_new, int* __restrict__ row_flag)
{
    // R15: fold the ws zeroing into this kernel (one fewer dispatch).
    const int tid = (int)(blockIdx.x * blockDim.x + threadIdx.x);
    if (tid < NN) { ej_new[tid] = 0; row_flag[tid] = 0; }

    int gw   = tid >> 6;               // global wave id == node id
    int lane = threadIdx.x & 63;
    if (gw >= NN) return;
    const float4* row = (const float4*)feats + (size_t)gw * D4;
    const float4* q4  = (const float4*)wq_w;
    const float4* k4  = (const float4*)wk_w;
    // lane owns elements [8*lane .. 8*lane+7]
    float4 v0 = row[2 * lane], v1 = row[2 * lane + 1];
    float4 q0 = q4[2 * lane],  q1 = q4[2 * lane + 1];
    float4 k0 = k4[2 * lane],  k1 = k4[2 * lane + 1];
    float dq = v0.x*q0.x + v0.y*q0.y + v0.z*q0.z + v0.w*q0.w
             + v1.x*q1.x + v1.y*q1.y + v1.z*q1.z + v1.w*q1.w;
    float dk = v0.x*k0.x + v0.y*k0.y + v0.z*k0.z + v0.w*k0.w
             + v1.x*k1.x + v1.y*k1.y + v1.z*k1.z + v1.w*k1.w;
#pragma unroll
    for (int off = 32; off > 0; off >>= 1) {
        dq += __shfl_down(dq, off, 64);
        dk += __shfl_down(dk, off, 64);
    }
    if (feats16) {
        v4u p;
        p.x = packh2(v0.x, v0.y); p.y = packh2(v0.z, v0.w);
        p.z = packh2(v1.x, v1.y); p.w = packh2(v1.z, v1.w);
        *(v4u*)(feats16 + (size_t)gw * DU16 + 4 * lane) = p;  // plain store;
        // visible to the attn kernel via stream-order kernel boundary.
    }
    if (lane == 0) {
        ei[gw]      = dq + wq_b[0];
        ej_orig[gw] = dk + wk_b[0];
    }
}

// ---------------- fp16-gather dataflow kernel (primary path) ----------------
__global__ __launch_bounds__(256, 4) void attn_dataflow_h16(
    const int* __restrict__ neighbors, const int* __restrict__ deg,
    const float* __restrict__ ei_arr, const float* __restrict__ ej_orig,
    const float* __restrict__ wk_b,
    const unsigned int* __restrict__ feats16, unsigned int* __restrict__ out16,
    int* ej_new, int* row_flag, float* out)
{
    const int lane   = threadIdx.x & 63;
    const int gwave  = (int)((blockIdx.x * blockDim.x + threadIdx.x) >> 6);
    const int nwaves = (int)((gridDim.x * blockDim.x) >> 6);
    const float   wkb = wk_b[0];

    if (gwave >= NN) return;

    // ---- software-pipelined FRONT: loads for the next id issued early ----
    int   d_nx   = deg[gwave];
    int   nbr_nx = (lane < K) ? neighbors[(size_t)gwave * K + lane] : 0;
    v4u   cp_nx  = *(const v4u*)(feats16 + (size_t)gwave * DU16 + 4 * lane);
    float eii_nx  = ei_arr[gwave];
    float ejoc_nx = ej_orig[gwave];

    for (int id = gwave; id < NN; id += nwaves) {
        const int d   = d_nx;
        const int nbr = nbr_nx;
        const v4u cp  = cp_nx;
        const float eii  = eii_nx;
        const float ejoc = ejoc_nx;

        const bool valid = lane < d;                 // d <= 32
        const bool isdep = valid && (nbr < id);

        float2 cf0 = unpackh2(cp.x), cf1 = unpackh2(cp.y);
        float2 cf2 = unpackh2(cp.z), cf3 = unpackh2(cp.w);
        const float4 c0 = {cf0.x, cf0.y, cf1.x, cf1.y};
        const float4 c1 = {cf2.x, cf2.y, cf3.x, cf3.y};

        float ejraw = 0.f, eij = -3.0e38f;
        if (valid && !isdep) { ejraw = ej_orig[nbr]; eij = eii * ejraw; }

        // ---------------- phase A: scalar chain ----------------
        unsigned long long wait = __ballot(isdep);
        while (wait) {
            int pv = 0;
            const bool w = (wait >> lane) & 1ULL;
            if (w) pv = __hip_atomic_load(&ej_new[nbr], __ATOMIC_RELAXED,
                                          __HIP_MEMORY_SCOPE_AGENT);
            unsigned long long ready = __ballot(w && pv != 0);
            if (w && pv != 0) { ejraw = __int_as_float(pv); eij = eii * ejraw; }
            wait &= ~ready;
            if (wait && !ready) __builtin_amdgcn_s_sleep(1);
        }
        // exact 2-pass softmax scalars (all eij known; invalid = -3e38)
        float m = eij;
#pragma unroll
        for (int off = 32; off > 0; off >>= 1)
            m = fmaxf(m, __shfl_xor(m, off, 64));
        const float wt = valid ? __expf(eij - m) : 0.f;
        float s = wt, se = wt * ejraw;
#pragma unroll
        for (int off = 32; off > 0; off >>= 1) {
            s  += __shfl_xor(s,  off, 64);
            se += __shfl_xor(se, off, 64);
        }
        const float inv_s = (s > 0.f) ? (1.0f / s) : 0.f;

        // publish ej_new NOW — scalar-only payload, no drain needed
        {
            const float ejn = ejoc + ((s > 0.f) ? (se * inv_s - wkb) : 0.f);
            int bits = __float_as_int(ejn);
            if (bits == 0) bits = 1;   // avoid the not-ready sentinel
            if (lane == 0)
                __hip_atomic_store(&ej_new[id], bits,
                                   __ATOMIC_RELAXED, __HIP_MEMORY_SCOPE_AGENT);
        }

        // ---- prefetch next id's FRONT (overlaps phase B's polls/gathers) ----
        {
            const int nid = id + nwaves;
            if (nid < NN) {
                d_nx   = deg[nid];
                nbr_nx = (lane < K) ? neighbors[(size_t)nid * K + lane] : 0;
                cp_nx  = *(const v4u*)(feats16 + (size_t)nid * DU16 + 4 * lane);
                eii_nx  = ei_arr[nid];
                ejoc_nx = ej_orig[nid];
            }
        }

        // ---------------- phase B: row chain ----------------
        float4 acc0 = {0.f, 0.f, 0.f, 0.f};
        float4 acc1 = {0.f, 0.f, 0.f, 0.f};
        unsigned long long pend  = __ballot(valid && !isdep);
        unsigned long long wait2 = __ballot(isdep);

        while (pend | wait2) {
            if (!pend) {
                int rv = 0;
                const bool w = (wait2 >> lane) & 1ULL;
                if (w) rv = __hip_atomic_load(&row_flag[nbr], __ATOMIC_RELAXED,
                                              __HIP_MEMORY_SCOPE_AGENT);
                unsigned long long ready = __ballot(w && rv != 0);
                if (!ready) { __builtin_amdgcn_s_sleep(1); continue; }
                pend = ready;
                wait2 &= ~ready;
            }
            // take up to 8 ready neighbors; static indexing, duplicates
            // clamp to the last valid slot and get weight 0.
            int js_[8]; float ww[8]; int klast = 0;
#pragma unroll
            for (int t = 0; t < 8; ++t) {
                const bool has = (pend != 0);            // wave-uniform
                int k = has ? ((int)__ffsll(pend) - 1) : klast;
                if (has) pend &= pend - 1;
                klast = k;
                float w8 = __shfl(wt, k, 64);
                ww[t]  = has ? w8 : 0.f;
                js_[t] = __shfl(nbr, k, 64);
            }
            v4u pv8[8];
#pragma unroll
            for (int t = 0; t < 8; ++t) {
                const unsigned int* sp = ((js_[t] < id) ? out16 : feats16)
                                         + (size_t)js_[t] * DU16 + 4 * lane;
                pv8[t] = *(const v4u*)sp;
            }
#pragma unroll
            for (int t = 0; t < 8; ++t) {
                const float a = ww[t];
                float2 f0 = unpackh2(pv8[t].x), f1 = unpackh2(pv8[t].y);
                float2 f2 = unpackh2(pv8[t].z), f3 = unpackh2(pv8[t].w);
                acc0.x += a * f0.x; acc0.y += a * f0.y;
                acc0.z += a * f1.x; acc0.w += a * f1.y;
                acc1.x += a * f2.x; acc1.y += a * f2.y;
                acc1.z += a * f3.x; acc1.w += a * f3.y;
            }
        }

        float4 g0 = {c0.x + acc0.x * inv_s, c0.y + acc0.y * inv_s,
                     c0.z + acc0.z * inv_s, c0.w + acc0.w * inv_s};
        float4 g1 = {c1.x + acc1.x * inv_s, c1.y + acc1.y * inv_s,
                     c1.z + acc1.z * inv_s, c1.w + acc1.w * inv_s};

        // f16 mirror row: the gather payload, write-through + flag-ordered
        v4u pg;
        pg.x = packh2(g0.x, g0.y); pg.y = packh2(g0.z, g0.w);
        pg.z = packh2(g1.x, g1.y); pg.w = packh2(g1.z, g1.w);
        store_u4_llc(out16 + (size_t)id * DU16 + 4 * lane, pg);

        // order the out16 payload (at LLC) before the row flag
        __builtin_amdgcn_s_waitcnt(0);
        if (lane == 0)
            __hip_atomic_store(&row_flag[id], 1,
                               __ATOMIC_RELAXED, __HIP_MEMORY_SCOPE_AGENT);

        // f32 result row: no device consumer -> plain cached stores, off-chain
        float4* orow4 = (float4*)out + (size_t)id * D4;
        orow4[2 * lane]     = g0;
        orow4[2 * lane + 1] = g1;
    }
}

// ---------------- f32 fallback (verbatim R5 kernel, 260us verified) ---------
__global__ __launch_bounds__(256, 4) void attn_dataflow_f32(
    const float* __restrict__ feats,
    const int* __restrict__ neighbors, const int* __restrict__ deg,
    const float* __restrict__ ei_arr, const float* __restrict__ ej_orig,
    const float* __restrict__ wk_w, const float* __restrict__ wk_b,
    int* ej_new, float* out)
{
    const int lane   = threadIdx.x & 63;
    const int gwave  = (int)((blockIdx.x * blockDim.x + threadIdx.x) >> 6);
    const int nwaves = (int)((gridDim.x * blockDim.x) >> 6);
    const float4* f4  = (const float4*)feats;
    const float4* o4r = (const float4*)out;
    const float4* wk4 = (const float4*)wk_w;
    const float   wkb = wk_b[0];

    for (int id = gwave; id < NN; id += nwaves) {
        const int d = deg[id];
        int nbr = 0;
        if (lane < K) nbr = neighbors[(size_t)id * K + lane];
        const bool valid = lane < d;
        const bool isdep = valid && (nbr < id);

        const float4 c0 = f4[(size_t)id * D4 + lane];
        const float4 c1 = f4[(size_t)id * D4 + lane + 64];
        const float eii = ei_arr[id];

        float eij = 0.f;
        if (valid && !isdep) eij = eii * ej_orig[nbr];

        float4 acc0 = {0.f, 0.f, 0.f, 0.f};
        float4 acc1 = {0.f, 0.f, 0.f, 0.f};
        float m = -3.0e38f, s = 0.f;

        unsigned long long pend = __ballot(valid && !isdep);
        unsigned long long wait = __ballot(isdep);

        while (pend | wait) {
            if (!pend) {
                int pv = 0;
                const bool w = (wait >> lane) & 1ULL;
                if (w) pv = __hip_atomic_load(&ej_new[nbr], __ATOMIC_RELAXED,
                                              __HIP_MEMORY_SCOPE_AGENT);
                unsigned long long ready = __ballot(w && pv != 0);
                if (!ready) { __builtin_amdgcn_s_sleep(1); continue; }
                if (w && pv != 0) eij = eii * __int_as_float(pv);
                pend = ready;
                wait &= ~ready;
            }
            int cnt = 0;
            int   js[4]; float ee[4];
#pragma unroll
            for (int t = 0; t < 4; ++t) {
                if (pend) {
                    int k = (int)__ffsll(pend) - 1;
                    pend &= pend - 1;
                    ee[cnt] = __shfl(eij, k, 64);
                    js[cnt] = __shfl(nbr, k, 64);
                    ++cnt;
                }
            }
            float4 v0[4], v1[4];
#pragma unroll
            for (int t = 0; t < 4; ++t) {
                if (t < cnt) {
                    const float4* sp = (js[t] < id) ? (o4r + (size_t)js[t] * D4)
                                                    : (f4  + (size_t)js[t] * D4);
                    v0[t] = sp[lane];
                    v1[t] = sp[lane + 64];
                }
            }
            float mb = m;
#pragma unroll
            for (int t = 0; t < 4; ++t) if (t < cnt) mb = fmaxf(mb, ee[t]);
            if (mb > m) {
                const float r = __expf(m - mb);
                acc0.x *= r; acc0.y *= r; acc0.z *= r; acc0.w *= r;
                acc1.x *= r; acc1.y *= r; acc1.z *= r; acc1.w *= r;
                s *= r; m = mb;
            }
#pragma unroll
            for (int t = 0; t < 4; ++t) {
                if (t < cnt) {
                    const float wt = __expf(ee[t] - m);
                    s += wt;
                    acc0.x += wt * v0[t].x; acc0.y += wt * v0[t].y;
                    acc0.z += wt * v0[t].z; acc0.w += wt * v0[t].w;
                    acc1.x += wt * v1[t].x; acc1.y += wt * v1[t].y;
                    acc1.z += wt * v1[t].z; acc1.w += wt * v1[t].w;
                }
            }
        }

        const float inv_s = (s > 0.f) ? (1.0f / s) : 0.f;
        float4 g0 = {c0.x + acc0.x * inv_s, c0.y + acc0.y * inv_s,
                     c0.z + acc0.z * inv_s, c0.w + acc0.w * inv_s};
        float4 g1 = {c1.x + acc1.x * inv_s, c1.y + acc1.y * inv_s,
                     c1.z + acc1.z * inv_s, c1.w + acc1.w * inv_s};
        float* orow = out + (size_t)id * D;
        store_f4_llc(orow + 4 * lane,        g0);
        store_f4_llc(orow + 4 * (lane + 64), g1);

        float4 w0 = wk4[lane], w1 = wk4[lane + 64];
        float pd = g0.x * w0.x + g0.y * w0.y + g0.z * w0.z + g0.w * w0.w
                 + g1.x * w1.x + g1.y * w1.y + g1.z * w1.z + g1.w * w1.w;
#pragma unroll
        for (int off = 32; off > 0; off >>= 1)
            pd += __shfl_xor(pd, off, 64);

        int bits = __float_as_int(pd + wkb);
        if (bits == 0) bits = 1;

        __builtin_amdgcn_s_waitcnt(0);
        if (lane == 0)
            __hip_atomic_store(&ej_new[id], bits,
                               __ATOMIC_RELAXED, __HIP_MEMORY_SCOPE_AGENT);
    }
}

extern "C" void kernel_launch(void* const* d_in, const int* in_sizes, int n_in,
                              void* d_out, int out_size, void* d_ws, size_t ws_size,
                              hipStream_t stream)
{
    const float* feats     = (const float*)d_in[0];
    const float* wq_w      = (const float*)d_in[1];
    const float* wq_b      = (const float*)d_in[2];
    const float* wk_w      = (const float*)d_in[3];
    const float* wk_b      = (const float*)d_in[4];
    const int*   neighbors = (const int*)d_in[5];
    const int*   deg       = (const int*)d_in[6];
    float*       out       = (float*)d_out;

    // ws: [ej_new: NN i][pad 64][row_flag: NN i][pad 64][ei: NN f][ej_orig: NN f]
    //     | align1024 | [feats16: NN*1KB][out16: NN*1KB]  (if ws_size allows)
    char*  ws       = (char*)d_ws;
    int*   ej_new   = (int*)ws;
    int*   row_flag = ej_new + NN + 64;
    float* ei       = (float*)(row_flag + NN + 64);
    float* ej_orig  = ei + NN;
    size_t scal_end = (size_t)((char*)(ej_orig + NN) - ws);
    size_t f16_off  = (scal_end + 1023) & ~(size_t)1023;
    size_t f16_need = 2ull * NN * DU16 * sizeof(unsigned int);  // 102.4 MB
    const bool use16 = (ws_size >= f16_off + f16_need);
    unsigned int* feats16 = (unsigned int*)(ws + f16_off);
    unsigned int* out16   = feats16 + (size_t)NN * DU16;

    // R15: no hipMemsetAsync — precomp zeroes ej_new/row_flag (tid<NN).
    dim3 pb(256), pg((NN + 3) / 4);
    precomp_kernel<<<pg, pb, 0, stream>>>(feats, wq_w, wq_b, wk_w, wk_b,
                                          ei, ej_orig,
                                          use16 ? feats16 : nullptr,
                                          ej_new, row_flag);

    if (use16) {
        attn_dataflow_h16<<<dim3(1024), dim3(256), 0, stream>>>(
            neighbors, deg, ei, ej_orig, wk_b,
            feats16, out16, ej_new, row_flag, out);
    } else {
        attn_dataflow_f32<<<dim3(1024), dim3(256), 0, stream>>>(
            feats, neighbors, deg, ei, ej_orig, wk_w, wk_b, ej_new, out);
    }
}